// Round 3
// baseline (415.838 us; speedup 1.0000x reference)
//
#include <hip/hip_runtime.h>
#include <math.h>
#include <stdint.h>

#define NSPH 7
#define NRAD 6
#define BLK  256

// ===== glibc sinf/cosf bit-exact replication =====
// (glibc sysdeps/ieee754/flt-32/{s_sinf.c,s_cosf.c,sincosf.h,sincosf_data.c},
//  ARM optimized-routines; baseline x86-64 build: f64 internals, NO fma)
#define SC_HPI_INV 0x1.45F306DC9C883p+23   /* 2/pi * 2^24 */
#define SC_HPI     0x1.921FB54442D18p+0
#define SC_C0      (0x1p+0)
#define SC_C1      (-0x1.ffffffd0c621cp-2)
#define SC_C2      (0x1.55553e1068f19p-5)
#define SC_C3      (-0x1.6c087e89a359dp-10)
#define SC_C4      (0x1.99343027bf8c3p-16)
#define SC_S1      (-0x1.555545995a603p-3)
#define SC_S2      (0x1.1107605230bc4p-7)
#define SC_S3      (-0x1.994eb3774cf24p-13)

__device__ __forceinline__ unsigned abstop12(float x) {
    return (__float_as_uint(x) >> 20) & 0x7ffu;
}

// quadrant-even branch: sine poly (doubles, explicit op order, no fma)
__device__ __forceinline__ float sp_sin(double x, double x2) {
    double x3 = __dmul_rn(x, x2);
    double s1 = __dadd_rn(SC_S2, __dmul_rn(x2, SC_S3));
    double x7 = __dmul_rn(x3, x2);
    double s  = __dadd_rn(x, __dmul_rn(x3, SC_S1));
    return (float)__dadd_rn(s, __dmul_rn(x7, s1));
}

// quadrant-odd branch: cosine poly; neg => table[1] (negated c coeffs)
__device__ __forceinline__ float sp_cos(double x2, bool neg) {
    double c0 = neg ? -SC_C0 : SC_C0;
    double c1 = neg ? -SC_C1 : SC_C1;
    double c2 = neg ? -SC_C2 : SC_C2;
    double c3 = neg ? -SC_C3 : SC_C3;
    double c4 = neg ? -SC_C4 : SC_C4;
    double x4  = __dmul_rn(x2, x2);
    double c2v = __dadd_rn(c3, __dmul_rn(x2, c4));
    double c1v = __dadd_rn(c0, __dmul_rn(x2, c1));
    double x6  = __dmul_rn(x4, x2);
    double c   = __dadd_rn(c1v, __dmul_rn(x4, c2));
    return (float)__dadd_rn(c, __dmul_rn(x6, c2v));
}

__device__ __forceinline__ double reduce_fast(double x, int* np) {
    double r = __dmul_rn(x, SC_HPI_INV);
    int n = (((int)r) + 0x800000) >> 24;
    *np = n;
    return __dsub_rn(x, __dmul_rn((double)n, SC_HPI));
}

__device__ __forceinline__ float glibc_sinf(float y) {
    unsigned at = abstop12(y);
    double x = (double)y;
    if (at < 0x3f4u) {                       // |y| < 0.78125
        if (at < 0x398u) return y;           // |y| < 0x1p-12
        return sp_sin(x, __dmul_rn(x, x));
    }
    int n;                                    // |y| < 120 always here
    double r = reduce_fast(x, &n);
    double s = ((n + 1) & 2) ? -1.0 : 1.0;   // sign[n&3] of {1,-1,-1,1}
    bool neg = (n & 2) != 0;
    double xs = __dmul_rn(r, s);
    double x2 = __dmul_rn(r, r);
    if ((n & 1) == 0) return sp_sin(xs, x2);
    return sp_cos(x2, neg);
}

__device__ __forceinline__ float glibc_cosf(float y) {
    unsigned at = abstop12(y);
    double x = (double)y;
    if (at < 0x3f4u) {
        if (at < 0x398u) return 1.0f;
        return sp_cos(__dmul_rn(x, x), false);
    }
    int n;
    double r = reduce_fast(x, &n);
    double s = ((n + 2) & 2) ? -1.0 : 1.0;   // sign[(n+1)&3]
    bool neg = ((n + 1) & 2) != 0;
    int m = n ^ 1;
    double xs = __dmul_rn(r, s);
    double x2 = __dmul_rn(r, r);
    if ((m & 1) == 0) return sp_sin(xs, x2);
    return sp_cos(x2, neg);
}

// ===== f64 spherical bessel j_n (for zeros/bnorm; replicates _sph_jn_np) =====
__device__ __forceinline__ double jn_f64(double x, int n) {
    double s = sin(x), c = cos(x);
    double j0 = s / x;
    if (n == 0) return j0;
    double j1 = s / (x * x) - c / x;
    double jm1 = j0, j = j1;
    for (int l = 1; l < n; ++l) {
        double t = (double)(2 * l + 1) / x * j - jm1;
        jm1 = j; j = t;
    }
    return j;
}

// Replicates _jn_zeros + _BNORM + _YNORM on device (f64, converged far below
// f32 ulp). cst layout (floats): [0..41] zf, [42..83] bnorm, [84..90] ynorm
__global__ __launch_bounds__(704) void setup_k(float* __restrict__ cst) {
    __shared__ double pts[13];
    __shared__ double roots[12];
    __shared__ double Z[NSPH][NRAD];
    const double PI = 3.141592653589793238462643383279502884;
    int tid = threadIdx.x, wv = tid >> 6, ln = tid & 63;
    if (tid < 12) pts[tid] = PI * (double)(tid + 1);
    __syncthreads();
    if (tid < NRAD) Z[0][tid] = pts[tid];
    for (int i = 1; i < NSPH; ++i) {
        int m = NRAD + NSPH - 1 - i;  // 12 - i
        if (wv < m) {
            double a = pts[wv], b = pts[wv + 1];
            for (int r = 0; r < 9; ++r) {
                double st = (b - a) * (1.0 / 63.0);
                double f = jn_f64(a + st * (double)ln, i);
                double f0 = __shfl(f, 0);
                unsigned long long bm = __ballot((ln > 0) && (f0 * f <= 0.0));
                int idx = bm ? (__ffsll((unsigned long long)bm) - 1) : 63;
                b = a + st * (double)idx;
                a = a + st * (double)(idx - 1);
            }
            if (ln == 0) roots[wv] = 0.5 * (a + b);
        }
        __syncthreads();
        if (tid < m) pts[tid] = roots[tid];
        if (tid < NRAD) Z[i][tid] = roots[tid];
        __syncthreads();
    }
    if (tid < NSPH * NRAD) {
        int l = tid / NRAD;
        double z = Z[l][tid % NRAD];
        cst[tid] = (float)z;
        double jp = jn_f64(z, l + 1);
        cst[42 + tid] = (float)(1.0 / sqrt(0.5 * (jp * jp)));
    }
    if (tid < NSPH) {
        cst[84 + tid] = (float)sqrt((double)(2 * tid + 1) / (4.0 * PI));
    }
}

__global__ __launch_bounds__(BLK) void sph_main(
    const float* __restrict__ D, const float* __restrict__ Ang,
    const int* __restrict__ id3, const float* __restrict__ cst,
    float* __restrict__ out, int nT)
{
    __shared__ float zf[42], bn[42], yn[7];
    __shared__ float stg[BLK * 42];
    int tid = threadIdx.x;
    if (tid < 42) { zf[tid] = cst[tid]; bn[tid] = cst[42 + tid]; }
    if (tid < 7)  { yn[tid] = cst[84 + tid]; }
    __syncthreads();
    int base = blockIdx.x * BLK;
    int t = base + tid;
    bool ok = t < nT;
    int e = ok ? id3[t] : 0;
    float Dv = D[e];
    float ang = ok ? Ang[t] : 0.0f;

    // d = D * (1/cutoff)  [f32 weak promotion, bit-exact]
    float d = __fmul_rn(Dv, 0.2f);
    // envelope: needs only ~1e-3 relative accuracy (multiplicative on output)
    float invd = __fdiv_rn(1.0f, d);
    float d2 = d * d, d4 = d2 * d2, d5 = d4 * d, d6 = d5 * d, d7 = d6 * d;
    float env = ((invd + (-28.0f) * d5) + 48.0f * d6) + (-21.0f) * d7;
    float u_d = (d < 1.0f) ? env : 0.0f;
    const float NC = (float)0.0894427190999916;  // 0.2**1.5
    float unc = __fmul_rn(u_d, NC);

    // ct = np.cos(angle) via glibc cosf; Legendre (exact op order)
    float ct = glibc_cosf(ang);
    float P[NSPH];
    P[0] = 1.0f; P[1] = ct;
#pragma unroll
    for (int l = 1; l < NSPH - 1; ++l) {
        float t1 = __fmul_rn(__fmul_rn((float)(2 * l + 1), ct), P[l]);
        float t2 = __fmul_rn((float)l, P[l - 1]);
        P[l + 1] = __fdiv_rn(__fsub_rn(t1, t2), (float)(l + 1));
    }

    float* row = &stg[tid * 42];
#pragma unroll
    for (int l = 0; l < NSPH; ++l) {
        float yP = __fmul_rn(yn[l], P[l]);
        for (int n = 0; n < NRAD; ++n) {
            float z = zf[l * 6 + n];
            float x = __fmul_rn(d, z);        // bit-exact chain input
            float s = glibc_sinf(x);
            // f32 recurrence, exact np op order, NO contraction
            float j = __fdiv_rn(s, x);
            if (l > 0) {
                float c = glibc_cosf(x);
                float x2 = __fmul_rn(x, x);
                float j1 = __fsub_rn(__fdiv_rn(s, x2), __fdiv_rn(c, x));
                float jm1 = j, jc = j1;
                for (int k = 1; k < l; ++k) {
                    float fk = __fdiv_rn((float)(2 * k + 1), x);
                    float jn2 = __fsub_rn(__fmul_rn(fk, jc), jm1);
                    jm1 = jc; jc = jn2;
                }
                j = jc;
            }
            float re = __fmul_rn(unc, __fmul_rn(bn[l * 6 + n], j));
            row[l * 6 + n] = __fmul_rn(re, yP);
        }
    }
    __syncthreads();
    // coalesced store of the block's contiguous 256x42 output slab
    int nv = nT - base; if (nv > BLK) nv = BLK;
    int nf2 = nv * 21;  // total float2s (42 floats/row)
    const float2* src = (const float2*)stg;
    float2* dst = (float2*)(out + (long long)base * 42);
    for (int i = tid; i < nf2; i += BLK) dst[i] = src[i];
}

extern "C" void kernel_launch(void* const* d_in, const int* in_sizes, int n_in,
                              void* d_out, int out_size, void* d_ws, size_t ws_size,
                              hipStream_t stream) {
    const float* D   = (const float*)d_in[0];
    const float* Ang = (const float*)d_in[1];
    const int*   id3 = (const int*)d_in[2];
    // d_in[3] (Kidx) unused by reference
    float* cst = (float*)d_ws;     // 91 floats
    float* out = (float*)d_out;
    int nT = in_sizes[1];

    setup_k<<<1, 704, 0, stream>>>(cst);
    int grid = (nT + BLK - 1) / BLK;
    sph_main<<<grid, BLK, 0, stream>>>(D, Ang, id3, cst, out, nT);
}

// Round 4
// 306.760 us; speedup vs baseline: 1.3556x; 1.3556x over previous
//
#include <hip/hip_runtime.h>
#include <math.h>
#include <stdint.h>

#define NSPH 7
#define NRAD 6
#define BLK  256
#define NE_PAD 48   // padded row: 192 B, 16B-aligned float4 loads

// ===== glibc sinf/cosf bit-exact replication =====
// (glibc sysdeps/ieee754/flt-32/{s_sinf.c,s_cosf.c,sincosf.h,sincosf_data.c},
//  baseline x86-64 build: f64 internals, NO fma) — verified PASS in round 3.
#define SC_HPI_INV 0x1.45F306DC9C883p+23   /* 2/pi * 2^24 */
#define SC_HPI     0x1.921FB54442D18p+0
#define SC_C0      (0x1p+0)
#define SC_C1      (-0x1.ffffffd0c621cp-2)
#define SC_C2      (0x1.55553e1068f19p-5)
#define SC_C3      (-0x1.6c087e89a359dp-10)
#define SC_C4      (0x1.99343027bf8c3p-16)
#define SC_S1      (-0x1.555545995a603p-3)
#define SC_S2      (0x1.1107605230bc4p-7)
#define SC_S3      (-0x1.994eb3774cf24p-13)

__device__ __forceinline__ unsigned abstop12(float x) {
    return (__float_as_uint(x) >> 20) & 0x7ffu;
}

__device__ __forceinline__ float sp_sin(double x, double x2) {
    double x3 = __dmul_rn(x, x2);
    double s1 = __dadd_rn(SC_S2, __dmul_rn(x2, SC_S3));
    double x7 = __dmul_rn(x3, x2);
    double s  = __dadd_rn(x, __dmul_rn(x3, SC_S1));
    return (float)__dadd_rn(s, __dmul_rn(x7, s1));
}

__device__ __forceinline__ float sp_cos(double x2, bool neg) {
    double c0 = neg ? -SC_C0 : SC_C0;
    double c1 = neg ? -SC_C1 : SC_C1;
    double c2 = neg ? -SC_C2 : SC_C2;
    double c3 = neg ? -SC_C3 : SC_C3;
    double c4 = neg ? -SC_C4 : SC_C4;
    double x4  = __dmul_rn(x2, x2);
    double c2v = __dadd_rn(c3, __dmul_rn(x2, c4));
    double c1v = __dadd_rn(c0, __dmul_rn(x2, c1));
    double x6  = __dmul_rn(x4, x2);
    double c   = __dadd_rn(c1v, __dmul_rn(x4, c2));
    return (float)__dadd_rn(c, __dmul_rn(x6, c2v));
}

__device__ __forceinline__ double reduce_fast(double x, int* np) {
    double r = __dmul_rn(x, SC_HPI_INV);
    int n = (((int)r) + 0x800000) >> 24;
    *np = n;
    return __dsub_rn(x, __dmul_rn((double)n, SC_HPI));
}

__device__ __forceinline__ float glibc_sinf(float y) {
    unsigned at = abstop12(y);
    double x = (double)y;
    if (at < 0x3f4u) {                       // |y| < 0.78125
        if (at < 0x398u) return y;           // |y| < 0x1p-12
        return sp_sin(x, __dmul_rn(x, x));
    }
    int n;
    double r = reduce_fast(x, &n);
    double s = ((n + 1) & 2) ? -1.0 : 1.0;
    bool neg = (n & 2) != 0;
    double xs = __dmul_rn(r, s);
    double x2 = __dmul_rn(r, r);
    if ((n & 1) == 0) return sp_sin(xs, x2);
    return sp_cos(x2, neg);
}

__device__ __forceinline__ float glibc_cosf(float y) {
    unsigned at = abstop12(y);
    double x = (double)y;
    if (at < 0x3f4u) {
        if (at < 0x398u) return 1.0f;
        return sp_cos(__dmul_rn(x, x), false);
    }
    int n;
    double r = reduce_fast(x, &n);
    double s = ((n + 2) & 2) ? -1.0 : 1.0;
    bool neg = ((n + 1) & 2) != 0;
    int m = n ^ 1;
    double xs = __dmul_rn(r, s);
    double x2 = __dmul_rn(r, r);
    if ((m & 1) == 0) return sp_sin(xs, x2);
    return sp_cos(x2, neg);
}

// ===== f64 spherical bessel (for zeros/bnorm; replicates _sph_jn_np) =====
__device__ __forceinline__ double jn_f64(double x, int n) {
    double s = sin(x), c = cos(x);
    double j0 = s / x;
    if (n == 0) return j0;
    double j1 = s / (x * x) - c / x;
    double jm1 = j0, j = j1;
    for (int l = 1; l < n; ++l) {
        double t = (double)(2 * l + 1) / x * j - jm1;
        jm1 = j; j = t;
    }
    return j;
}

// cst layout (floats): [0..41] zf, [42..83] bnorm, [84..90] ynorm
__global__ __launch_bounds__(704) void setup_k(float* __restrict__ cst) {
    __shared__ double pts[13];
    __shared__ double roots[12];
    __shared__ double Z[NSPH][NRAD];
    const double PI = 3.141592653589793238462643383279502884;
    int tid = threadIdx.x, wv = tid >> 6, ln = tid & 63;
    if (tid < 12) pts[tid] = PI * (double)(tid + 1);
    __syncthreads();
    if (tid < NRAD) Z[0][tid] = pts[tid];
    for (int i = 1; i < NSPH; ++i) {
        int m = NRAD + NSPH - 1 - i;  // 12 - i
        if (wv < m) {
            double a = pts[wv], b = pts[wv + 1];
            for (int r = 0; r < 9; ++r) {
                double st = (b - a) * (1.0 / 63.0);
                double f = jn_f64(a + st * (double)ln, i);
                double f0 = __shfl(f, 0);
                unsigned long long bm = __ballot((ln > 0) && (f0 * f <= 0.0));
                int idx = bm ? (__ffsll((unsigned long long)bm) - 1) : 63;
                b = a + st * (double)idx;
                a = a + st * (double)(idx - 1);
            }
            if (ln == 0) roots[wv] = 0.5 * (a + b);
        }
        __syncthreads();
        if (tid < m) pts[tid] = roots[tid];
        if (tid < NRAD) Z[i][tid] = roots[tid];
        __syncthreads();
    }
    if (tid < NSPH * NRAD) {
        int l = tid / NRAD;
        double z = Z[l][tid % NRAD];
        cst[tid] = (float)z;
        double jp = jn_f64(z, l + 1);
        cst[42 + tid] = (float)(1.0 / sqrt(0.5 * (jp * jp)));
    }
    if (tid < NSPH) {
        cst[84 + tid] = (float)sqrt((double)(2 * tid + 1) / (4.0 * PI));
    }
}

// ===== Phase A: per-(edge, l, n) rbf_env table, bit-exact chain =====
__global__ __launch_bounds__(BLK) void edge_k(
    const float* __restrict__ D, const float* __restrict__ cst,
    float* __restrict__ tab, int nE)
{
    __shared__ float zf[42], bn[42];
    int tid = threadIdx.x;
    if (tid < 42) { zf[tid] = cst[tid]; bn[tid] = cst[42 + tid]; }
    __syncthreads();
    int gid = blockIdx.x * BLK + tid;
    if (gid >= nE * 42) return;
    int e = gid / 42;
    int k = gid - e * 42;
    int l = k / 6;

    float d = __fmul_rn(D[e], 0.2f);
    float invd = __fdiv_rn(1.0f, d);
    float d2 = d * d, d4 = d2 * d2, d5 = d4 * d, d6 = d5 * d, d7 = d6 * d;
    float env = ((invd + (-28.0f) * d5) + 48.0f * d6) + (-21.0f) * d7;
    float u_d = (d < 1.0f) ? env : 0.0f;
    const float NC = (float)0.0894427190999916;  // 0.2**1.5
    float unc = __fmul_rn(u_d, NC);

    float x = __fmul_rn(d, zf[k]);
    float s = glibc_sinf(x);
    float j = __fdiv_rn(s, x);
    if (l > 0) {
        float c = glibc_cosf(x);
        float x2 = __fmul_rn(x, x);
        float j1 = __fsub_rn(__fdiv_rn(s, x2), __fdiv_rn(c, x));
        float jm1 = j, jc = j1;
        for (int kk = 1; kk < l; ++kk) {
            float fk = __fdiv_rn((float)(2 * kk + 1), x);
            float jn2 = __fsub_rn(__fmul_rn(fk, jc), jm1);
            jm1 = jc; jc = jn2;
        }
        j = jc;
    }
    tab[(long long)e * NE_PAD + k] = __fmul_rn(unc, __fmul_rn(bn[k], j));
}

// ===== Phase B: gather + sph multiply + coalesced store =====
__global__ __launch_bounds__(BLK) void trip_k(
    const float* __restrict__ Ang, const int* __restrict__ id3,
    const float* __restrict__ tab, const float* __restrict__ cst,
    float* __restrict__ out, int nT)
{
    __shared__ float yn[7];
    __shared__ float stg[BLK * 42];
    int tid = threadIdx.x;
    if (tid < 7) yn[tid] = cst[84 + tid];
    __syncthreads();
    int base = blockIdx.x * BLK;
    int t = base + tid;
    bool ok = t < nT;
    int e = ok ? id3[t] : 0;
    float ang = ok ? Ang[t] : 0.0f;

    // identical numerics to round-3 kernel (bit-exact output)
    float ct = glibc_cosf(ang);
    float P[NSPH];
    P[0] = 1.0f; P[1] = ct;
#pragma unroll
    for (int l = 1; l < NSPH - 1; ++l) {
        float t1 = __fmul_rn(__fmul_rn((float)(2 * l + 1), ct), P[l]);
        float t2 = __fmul_rn((float)l, P[l - 1]);
        P[l + 1] = __fdiv_rn(__fsub_rn(t1, t2), (float)(l + 1));
    }
    float yP[NSPH];
#pragma unroll
    for (int l = 0; l < NSPH; ++l) yP[l] = __fmul_rn(yn[l], P[l]);

    const float4* rowv = (const float4*)(tab + (long long)e * NE_PAD);
    float* row = &stg[tid * 42];
#pragma unroll
    for (int w = 0; w < 10; ++w) {
        float4 v = rowv[w];
        int k = w * 4;
        row[k + 0] = __fmul_rn(v.x, yP[(k + 0) / 6]);
        row[k + 1] = __fmul_rn(v.y, yP[(k + 1) / 6]);
        row[k + 2] = __fmul_rn(v.z, yP[(k + 2) / 6]);
        row[k + 3] = __fmul_rn(v.w, yP[(k + 3) / 6]);
    }
    {
        float2 v = ((const float2*)rowv)[20];
        row[40] = __fmul_rn(v.x, yP[6]);
        row[41] = __fmul_rn(v.y, yP[6]);
    }
    __syncthreads();
    int nv = nT - base; if (nv > BLK) nv = BLK;
    int nf2 = nv * 21;
    const float2* src = (const float2*)stg;
    float2* dst = (float2*)(out + (long long)base * 42);
    for (int i = tid; i < nf2; i += BLK) dst[i] = src[i];
}

// ===== fallback: round-3 fused kernel (used only if ws too small) =====
__global__ __launch_bounds__(BLK) void sph_main(
    const float* __restrict__ D, const float* __restrict__ Ang,
    const int* __restrict__ id3, const float* __restrict__ cst,
    float* __restrict__ out, int nT)
{
    __shared__ float zf[42], bn[42], yn[7];
    __shared__ float stg[BLK * 42];
    int tid = threadIdx.x;
    if (tid < 42) { zf[tid] = cst[tid]; bn[tid] = cst[42 + tid]; }
    if (tid < 7)  { yn[tid] = cst[84 + tid]; }
    __syncthreads();
    int base = blockIdx.x * BLK;
    int t = base + tid;
    bool ok = t < nT;
    int e = ok ? id3[t] : 0;
    float Dv = D[e];
    float ang = ok ? Ang[t] : 0.0f;
    float d = __fmul_rn(Dv, 0.2f);
    float invd = __fdiv_rn(1.0f, d);
    float d2 = d * d, d4 = d2 * d2, d5 = d4 * d, d6 = d5 * d, d7 = d6 * d;
    float env = ((invd + (-28.0f) * d5) + 48.0f * d6) + (-21.0f) * d7;
    float u_d = (d < 1.0f) ? env : 0.0f;
    const float NC = (float)0.0894427190999916;
    float unc = __fmul_rn(u_d, NC);
    float ct = glibc_cosf(ang);
    float P[NSPH];
    P[0] = 1.0f; P[1] = ct;
#pragma unroll
    for (int l = 1; l < NSPH - 1; ++l) {
        float t1 = __fmul_rn(__fmul_rn((float)(2 * l + 1), ct), P[l]);
        float t2 = __fmul_rn((float)l, P[l - 1]);
        P[l + 1] = __fdiv_rn(__fsub_rn(t1, t2), (float)(l + 1));
    }
    float* row = &stg[tid * 42];
#pragma unroll
    for (int l = 0; l < NSPH; ++l) {
        float yPl = __fmul_rn(yn[l], P[l]);
        for (int n = 0; n < NRAD; ++n) {
            float z = zf[l * 6 + n];
            float x = __fmul_rn(d, z);
            float s = glibc_sinf(x);
            float j = __fdiv_rn(s, x);
            if (l > 0) {
                float c = glibc_cosf(x);
                float x2 = __fmul_rn(x, x);
                float j1 = __fsub_rn(__fdiv_rn(s, x2), __fdiv_rn(c, x));
                float jm1 = j, jc = j1;
                for (int kk = 1; kk < l; ++kk) {
                    float fk = __fdiv_rn((float)(2 * kk + 1), x);
                    float jn2 = __fsub_rn(__fmul_rn(fk, jc), jm1);
                    jm1 = jc; jc = jn2;
                }
                j = jc;
            }
            float re = __fmul_rn(unc, __fmul_rn(bn[l * 6 + n], j));
            row[l * 6 + n] = __fmul_rn(re, yPl);
        }
    }
    __syncthreads();
    int nv = nT - base; if (nv > BLK) nv = BLK;
    int nf2 = nv * 21;
    const float2* src = (const float2*)stg;
    float2* dst = (float2*)(out + (long long)base * 42);
    for (int i = tid; i < nf2; i += BLK) dst[i] = src[i];
}

extern "C" void kernel_launch(void* const* d_in, const int* in_sizes, int n_in,
                              void* d_out, int out_size, void* d_ws, size_t ws_size,
                              hipStream_t stream) {
    const float* D   = (const float*)d_in[0];
    const float* Ang = (const float*)d_in[1];
    const int*   id3 = (const int*)d_in[2];
    float* out = (float*)d_out;
    int nE = in_sizes[0];
    int nT = in_sizes[1];

    size_t tab_bytes = (size_t)nE * NE_PAD * sizeof(float);
    if (ws_size >= tab_bytes + 512) {
        float* tab = (float*)d_ws;
        float* cst = (float*)((char*)d_ws + tab_bytes);
        setup_k<<<1, 704, 0, stream>>>(cst);
        int gA = (nE * 42 + BLK - 1) / BLK;
        edge_k<<<gA, BLK, 0, stream>>>(D, cst, tab, nE);
        int gB = (nT + BLK - 1) / BLK;
        trip_k<<<gB, BLK, 0, stream>>>(Ang, id3, tab, cst, out, nT);
    } else {
        float* cst = (float*)d_ws;   // 91 floats
        setup_k<<<1, 704, 0, stream>>>(cst);
        int grid = (nT + BLK - 1) / BLK;
        sph_main<<<grid, BLK, 0, stream>>>(D, Ang, id3, cst, out, nT);
    }
}